// Round 2
// baseline (847.283 us; speedup 1.0000x reference)
//
#include <hip/hip_runtime.h>
#include <math.h>

#define NNODES  200000
#define NEDGES  6400000
#define NGRAPHS 512
#define FIN     92
#define WID     10
#define HPAD    16                     // hs row padded to 16 floats (64 B)
#define NBLK    ((NNODES + 255) / 256) // 782

// partition geometry
#define LBITS   10
#define LSIZE   1024                   // dst nodes per bucket
#define LMASK   (LSIZE - 1)
#define NB      196                    // ceil(200000/1024) buckets
#define PBLK    512                    // partition blocks
#define EPB     (NEDGES / PBLK)        // 12500 edges per partition block (exact)
#define TILE    2500                   // staging tile (EPB = 5 * TILE exactly)
#define NTILE   (EPB / TILE)           // 5
#define CELLS   (2 * NB)               // 392 (dst plane + src plane)
#define CNT_N   (CELLS * PBLK)         // 200,704 scan elements
#define SBLKS   (CNT_N / 256)          // 784 scan blocks (exact)

// chunk-ordered rows (for k_agg1 gather locality)
#define CHBITS  14
#define NCHK    13                     // ceil(200000/16384) src chunks

// round-9: sub-bucket CSR build. k_bucket_csr at 196 blocks was 8% occupancy
// (grid-starved: 196 < 256 CUs) and wrote 253 MB vs 53 MB useful (scattered
// 8 B stores -> partial-line write amplification). Split each 1024-node
// bucket into 8 x 128-node sub-buckets: 1600-block grid, per-sub key space
// 1664, output staged in LDS then written COALESCED.
#define NSUB    1563                   // ceil(200000/128) sub-buckets
#define SUBW    1600                   // subscan storage (incl sentinel, padded)
#define SKEYS   (128 * NCHK)           // 1664 keys per sub-bucket
#define SKPAD   1792                   // 256*7 padded key array
#define SKPT    7                      // keys per thread in scan
#define SMAX    5120                   // LDS staging cap: mean 4096 + 16 sigma
#define CSR_GRID 1600                  // 8 q-slices * 200 parent slots
                                       // (blockIdx%8 == parent%8 -> siblings
                                       //  share an XCD under round-robin)

// multi-lane aggregation (round-8): 8 lanes per node, butterfly reduce.
#define LPN     8
#define LPNSH   3
#define NPB     (256 / LPN)            // 32 nodes per block
#define AGG_BLKS (NNODES / NPB)        // 6250 (exact)

// ---------------------------------------------------------------------------
// P1: per-(bucket,block) counts via LDS histograms. ZERO global atomics on
// the hot path. Round-9: histogram at sub-bucket (128-node) granularity;
// per-bucket counts for the scatter are the 8-way sums (cnt values
// identical to before), and sub-bucket totals accumulate into subcnt.
// ---------------------------------------------------------------------------
__global__ void k_part_count(const int* __restrict__ src,
                             const int* __restrict__ dst,
                             int* __restrict__ cnt,
                             int* __restrict__ subcnt) {
    __shared__ int hSub[NSUB];
    __shared__ int hS[NB];
    int tid = threadIdx.x, k = blockIdx.x;
    for (int i = tid; i < NSUB; i += 256) hSub[i] = 0;
    if (tid < NB) hS[tid] = 0;
    __syncthreads();
    int base = k * EPB;
    for (int i = tid; i < EPB; i += 256) {
        int e = base + i;
        atomicAdd(&hSub[dst[e] >> 7], 1);
        atomicAdd(&hS[src[e] >> LBITS], 1);
    }
    __syncthreads();
    if (tid < NB) {
        int s = 0;
        int b0 = tid * 8;
#pragma unroll
        for (int j = 0; j < 8; j++) {
            int ix = b0 + j;
            if (ix < NSUB) s += hSub[ix];
        }
        cnt[tid * PBLK + k] = s;
        cnt[(NB + tid) * PBLK + k] = hS[tid];
    }
    for (int i = tid; i < NSUB; i += 256) {
        int v = hSub[i];
        if (v) atomicAdd(&subcnt[i], v);
    }
}

// ---------------------------------------------------------------------------
// Scan step 1: per-block (256-elem) partial sums of cnt
// ---------------------------------------------------------------------------
__global__ void k_scan_partial(const int* __restrict__ cnt,
                               int* __restrict__ partial) {
    __shared__ int sdata[256];
    int tid = threadIdx.x;
    sdata[tid] = cnt[blockIdx.x * 256 + tid];
    __syncthreads();
    for (int s = 128; s > 0; s >>= 1) {
        if (tid < s) sdata[tid] += sdata[tid + s];
        __syncthreads();
    }
    if (tid == 0) partial[blockIdx.x] = sdata[0];
}

// ---------------------------------------------------------------------------
// Scan step 2: single-block exclusive scan of the 784 partials
// ---------------------------------------------------------------------------
__global__ void k_scan_top(int* __restrict__ partial) {
    __shared__ int buf[1024];
    __shared__ int carry_s;
    if (threadIdx.x == 0) carry_s = 0;
    __syncthreads();
    for (int base = 0; base < SBLKS; base += 1024) {
        int i = base + threadIdx.x;
        int c = carry_s;
        int orig = (i < SBLKS) ? partial[i] : 0;
        buf[threadIdx.x] = orig;
        __syncthreads();
        for (int off = 1; off < 1024; off <<= 1) {
            int t = (threadIdx.x >= off) ? buf[threadIdx.x - off] : 0;
            __syncthreads();
            buf[threadIdx.x] += t;
            __syncthreads();
        }
        if (i < SBLKS) partial[i] = buf[threadIdx.x] - orig + c;
        __syncthreads();
        if (threadIdx.x == 0) carry_s = c + buf[1023];
        __syncthreads();
    }
}

// ---------------------------------------------------------------------------
// Scan step 3: apply -- in-place exclusive scan of cnt
// ---------------------------------------------------------------------------
__global__ void k_scan_apply(int* __restrict__ cnt,
                             const int* __restrict__ partial) {
    __shared__ int buf[256];
    int tid = threadIdx.x;
    int i = blockIdx.x * 256 + tid;
    int v = cnt[i];
    buf[tid] = v;
    __syncthreads();
    for (int off = 1; off < 256; off <<= 1) {
        int t = (tid >= off) ? buf[tid - off] : 0;
        __syncthreads();
        buf[tid] += t;
        __syncthreads();
    }
    cnt[i] = buf[tid] - v + partial[blockIdx.x];
}

// ---------------------------------------------------------------------------
// Round-9: exclusive scan of the 1563 sub-bucket counts -> absolute csr
// starts (csr order is ascending dst, so the global scan IS the offset).
// Single block; sentinel subcnt[NSUB] = NEDGES.
// ---------------------------------------------------------------------------
__global__ void k_subscan(int* __restrict__ subcnt) {
    __shared__ int sbuf[256];
    int tid = threadIdx.x;
    int vals[SKPT];
    int sum = 0;
#pragma unroll
    for (int j = 0; j < SKPT; j++) {
        int c = tid * SKPT + j;
        int v = (c < NSUB) ? subcnt[c] : 0;
        vals[j] = v;
        sum += v;
    }
    sbuf[tid] = sum;
    __syncthreads();
    for (int off = 1; off < 256; off <<= 1) {
        int t = (tid >= off) ? sbuf[tid - off] : 0;
        __syncthreads();
        sbuf[tid] += t;
        __syncthreads();
    }
    int run = sbuf[tid] - sum;
#pragma unroll
    for (int j = 0; j < SKPT; j++) {
        int c = tid * SKPT + j;
        if (c < NSUB) {
            subcnt[c] = run;
            run += vals[j];
        }
    }
    if (tid == 0) subcnt[NSUB] = NEDGES;
}

// ---------------------------------------------------------------------------
// P2: TILE-STAGED scatter. Per 2500-edge tile: LDS hist -> LDS scan ->
// snapshot global cursors -> place records cell-ordered in LDS staging with
// precomputed destinations -> coalesced copy-out. ZERO global atomics.
// ---------------------------------------------------------------------------
__global__ void k_part_scatter(const float* __restrict__ r,
                               const int* __restrict__ src,
                               const int* __restrict__ dst,
                               const int* __restrict__ cnt,
                               float2* __restrict__ dstpart,
                               unsigned short* __restrict__ srcpart) {
    __shared__ int curD[NB], curS[NB];     // running global cursors
    __shared__ int hD[NB], hS[NB];         // tile hist, then tile cursor
    __shared__ int baseD[NB], baseS[NB];   // tile-local exclusive base
    __shared__ int segD[NB], segS[NB];     // global cursor snapshot at tile start
    __shared__ int sbuf[256];
    __shared__ float2 stD[TILE];           // 20 KB staged dst records
    __shared__ int    ddD[TILE];           // 10 KB their global slots
    __shared__ unsigned short stS[TILE];   // 5 KB staged src locals
    __shared__ int    ddS[TILE];           // 10 KB their global slots

    int tid = threadIdx.x, k = blockIdx.x;
    if (tid < NB) {
        curD[tid] = cnt[tid * PBLK + k];
        curS[tid] = cnt[(NB + tid) * PBLK + k] - NEDGES;
    }
    __syncthreads();

    int base = k * EPB;
    for (int t = 0; t < NTILE; t++) {
        int tbase = base + t * TILE;
        if (tid < NB) { hD[tid] = 0; hS[tid] = 0; }
        __syncthreads();
        // pass A: tile histograms
        for (int i = tid; i < TILE; i += 256) {
            int e = tbase + i;
            atomicAdd(&hD[dst[e] >> LBITS], 1);
            atomicAdd(&hS[src[e] >> LBITS], 1);
        }
        __syncthreads();
        // scan hD -> baseD; snapshot/advance global cursors
        int v = (tid < NB) ? hD[tid] : 0;
        sbuf[tid] = v;
        __syncthreads();
        for (int off = 1; off < 256; off <<= 1) {
            int tv = (tid >= off) ? sbuf[tid - off] : 0;
            __syncthreads();
            sbuf[tid] += tv;
            __syncthreads();
        }
        if (tid < NB) { baseD[tid] = sbuf[tid] - v; segD[tid] = curD[tid]; }
        __syncthreads();
        int v2 = (tid < NB) ? hS[tid] : 0;
        sbuf[tid] = v2;
        __syncthreads();
        for (int off = 1; off < 256; off <<= 1) {
            int tv = (tid >= off) ? sbuf[tid - off] : 0;
            __syncthreads();
            sbuf[tid] += tv;
            __syncthreads();
        }
        if (tid < NB) {
            baseS[tid] = sbuf[tid] - v2;
            segS[tid] = curS[tid];
            curD[tid] += hD[tid];
            curS[tid] += hS[tid];
            hD[tid] = baseD[tid];   // reuse as tile cursor
            hS[tid] = baseS[tid];
        }
        __syncthreads();
        // pass B: stage records cell-ordered, precompute global destinations
        for (int i = tid; i < TILE; i += 256) {
            int e = tbase + i;
            int s = src[e], d = dst[e];
            float x = r[3 * e + 0];
            float y = r[3 * e + 1];
            float z = r[3 * e + 2];
            float w = expf(-(x * x + y * y + z * z));
            int cd = d >> LBITS;
            int idx = atomicAdd(&hD[cd], 1);
            stD[idx] = make_float2(w, __int_as_float((s << LBITS) | (d & LMASK)));
            ddD[idx] = segD[cd] + (idx - baseD[cd]);
            int cs = s >> LBITS;
            int ids = atomicAdd(&hS[cs], 1);
            stS[ids] = (unsigned short)(s & LMASK);
            ddS[ids] = segS[cs] + (ids - baseS[cs]);
        }
        __syncthreads();
        // pass C: coalesced copy-out
        for (int i = tid; i < TILE; i += 256) {
            dstpart[ddD[i]] = stD[i];
            srcpart[ddS[i]] = stS[i];
        }
        __syncthreads();
    }
}

// ---------------------------------------------------------------------------
// P3s: per-bucket out-degree histogram (LDS) -> inv_sqrt_out.
// Runs BEFORE k_bucket_csr because srcpart aliases the csr region.
// ---------------------------------------------------------------------------
__global__ void k_bucket_odeg(const unsigned short* __restrict__ srcpart,
                              const int* __restrict__ cnt,
                              float* __restrict__ inv_out) {
    __shared__ int hist[LSIZE];
    int tid = threadIdx.x, b = blockIdx.x;
    int bstart = cnt[(NB + b) * PBLK] - NEDGES;
    int bend = (b == NB - 1) ? NEDGES : (cnt[(NB + b + 1) * PBLK] - NEDGES);
    for (int l = tid; l < LSIZE; l += 256) hist[l] = 0;
    __syncthreads();
    for (int p = bstart + tid; p < bend; p += 256)
        atomicAdd(&hist[srcpart[p]], 1);
    __syncthreads();
    for (int l = tid; l < LSIZE; l += 256) {
        int n = (b << LBITS) + l;
        if (n < NNODES) {
            int c = hist[l];
            inv_out[n] = rsqrtf((float)(c < 1 ? 1 : c));
        }
    }
}

// ---------------------------------------------------------------------------
// P3d round-9: sub-bucket CSR build. Block (q, par) filters the q-th eighth
// (by dst bits [7:9]) of parent bucket par's records, counting-sorts them by
// joint key (local7 * 13 + srcChunk), stages the result in LDS and writes
// csr COALESCED. Occupancy: 1600 blocks, 48 KB LDS -> 3 blocks/CU.
// ---------------------------------------------------------------------------
__global__ void k_bucket_csr(const float2* __restrict__ dstpart,
                             const int* __restrict__ subscan,
                             float2* __restrict__ csr,
                             int* __restrict__ row_ptr,
                             float* __restrict__ inv_in) {
    __shared__ int hist[SKPAD];      // 7,168 B
    __shared__ int sbuf[256];        // 1,024 B
    __shared__ float2 stout[SMAX];   // 40,960 B
    int tid = threadIdx.x;
    int q = blockIdx.x / 200;        // 0..7
    int par = blockIdx.x % 200;      // parent bucket slot
    if (par >= NB) return;           // uniform early-exit (pre-barrier)
    int sub = par * 8 + q;
    if (sub >= NSUB) return;
    int bstart = subscan[par * 8];
    int pe = par * 8 + 8;
    int bend = subscan[pe > NSUB ? NSUB : pe];
    int substart = subscan[sub];
    int subend = subscan[sub + 1];
    int sz = subend - substart;

    for (int j = tid; j < SKPAD; j += 256) hist[j] = 0;
    __syncthreads();
    // count own-sub keys over the parent range (reads are coalesced; the
    // 8 siblings share blockIdx%8 -> same XCD, so re-reads are L2-hits)
    for (int p = bstart + tid; p < bend; p += 256) {
        unsigned pk = __float_as_uint(dstpart[p].y);
        if (((pk >> 7) & 7u) == (unsigned)q)
            atomicAdd(&hist[(pk & 127u) * NCHK + (pk >> 24)], 1);
    }
    __syncthreads();
    // exclusive scan over the 1792 (padded) keys
    int kb = tid * SKPT;
    int sum = 0;
#pragma unroll
    for (int j = 0; j < SKPT; j++) sum += hist[kb + j];
    sbuf[tid] = sum;
    __syncthreads();
    for (int off = 1; off < 256; off <<= 1) {
        int tv = (tid >= off) ? sbuf[tid - off] : 0;
        __syncthreads();
        sbuf[tid] += tv;
        __syncthreads();
    }
    int run = sbuf[tid] - sum + substart;   // global cursor for own keys
#pragma unroll
    for (int j = 0; j < SKPT; j++) {
        int c = hist[kb + j];
        hist[kb + j] = run;
        run += c;
    }
    __syncthreads();
    // rows: start = cursor at key l*NCHK (read BEFORE placement mutates)
    if (tid < 128) {
        int l = tid;
        int rs = hist[l * NCHK];
        int re = (l == 127) ? subend : hist[(l + 1) * NCHK];
        int n = (sub << 7) + l;
        if (n < NNODES) {
            row_ptr[n] = rs;
            int c = re - rs;
            inv_in[n] = rsqrtf((float)(c < 1 ? 1 : c));
        }
    }
    __syncthreads();
    // placement
    if (sz <= SMAX) {
        for (int p = bstart + tid; p < bend; p += 256) {
            float2 rec = dstpart[p];
            unsigned pk = __float_as_uint(rec.y);
            if (((pk >> 7) & 7u) != (unsigned)q) continue;
            int pos = atomicAdd(&hist[(pk & 127u) * NCHK + (pk >> 24)], 1);
            stout[pos - substart] = make_float2(rec.x, __int_as_float((int)(pk >> LBITS)));
        }
        __syncthreads();
        // coalesced copy-out
        for (int i = tid; i < sz; i += 256)
            csr[substart + i] = stout[i];
    } else {
        // overflow fallback (statistically unreachable: SMAX = mean + 16 sigma)
        for (int p = bstart + tid; p < bend; p += 256) {
            float2 rec = dstpart[p];
            unsigned pk = __float_as_uint(rec.y);
            if (((pk >> 7) & 7u) != (unsigned)q) continue;
            int pos = atomicAdd(&hist[(pk & 127u) * NCHK + (pk >> 24)], 1);
            csr[pos] = make_float2(rec.x, __int_as_float((int)(pk >> LBITS)));
        }
    }
}

// ---------------------------------------------------------------------------
// K5: hs[n,:] = (A[n,:] @ W_emb + b_emb) * inv_sqrt_out[n], padded rows
// ---------------------------------------------------------------------------
__global__ void k_embed(const float* __restrict__ A,
                        const float* __restrict__ Wemb,
                        const float* __restrict__ bemb,
                        const float* __restrict__ inv_out,
                        float* __restrict__ hs) {
    __shared__ float sW[FIN * WID];
    __shared__ float sb[WID];
    for (int i = threadIdx.x; i < FIN * WID; i += blockDim.x) sW[i] = Wemb[i];
    if (threadIdx.x < WID) sb[threadIdx.x] = bemb[threadIdx.x];
    __syncthreads();

    int n = blockIdx.x * blockDim.x + threadIdx.x;
    if (n >= NNODES) return;

    float acc[WID];
#pragma unroll
    for (int k = 0; k < WID; k++) acc[k] = sb[k];

    const float4* row4 = reinterpret_cast<const float4*>(A + (size_t)n * FIN);
#pragma unroll
    for (int f4 = 0; f4 < FIN / 4; f4++) {
        float4 v = row4[f4];
        int f = f4 * 4;
#pragma unroll
        for (int k = 0; k < WID; k++) acc[k] += v.x * sW[(f + 0) * WID + k];
#pragma unroll
        for (int k = 0; k < WID; k++) acc[k] += v.y * sW[(f + 1) * WID + k];
#pragma unroll
        for (int k = 0; k < WID; k++) acc[k] += v.z * sW[(f + 2) * WID + k];
#pragma unroll
        for (int k = 0; k < WID; k++) acc[k] += v.w * sW[(f + 3) * WID + k];
    }

    float sc = inv_out[n];
    float* out = hs + (size_t)n * HPAD;
    float4 o0 = make_float4(acc[0] * sc, acc[1] * sc, acc[2] * sc, acc[3] * sc);
    float4 o1 = make_float4(acc[4] * sc, acc[5] * sc, acc[6] * sc, acc[7] * sc);
    float2 o2 = make_float2(acc[8] * sc, acc[9] * sc);
    *reinterpret_cast<float4*>(out + 0) = o0;
    *reinterpret_cast<float4*>(out + 4) = o1;
    *reinterpret_cast<float2*>(out + 8) = o2;
}

// ---------------------------------------------------------------------------
// K7: pull-mode aggregate of gconv1 FUSED with node update + gconv2 proj.
// 8 lanes per node (round-8), phase-locked chunk walk, butterfly reduce.
// ---------------------------------------------------------------------------
__global__ void k_agg1(const float2* __restrict__ csr,
                       const int* __restrict__ row_ptr,
                       const float* __restrict__ hs,
                       const float* __restrict__ W1,
                       const float* __restrict__ b1,
                       const float* __restrict__ W2,
                       const float* __restrict__ inv_in,
                       const float* __restrict__ inv_out,
                       float* __restrict__ sproj) {
    __shared__ float sW1[WID * WID];
    __shared__ float sb1[WID];
    __shared__ float sW2[WID];
    for (int i = threadIdx.x; i < WID * WID; i += blockDim.x) sW1[i] = W1[i];
    if (threadIdx.x < WID) {
        sb1[threadIdx.x] = b1[threadIdx.x];
        sW2[threadIdx.x] = W2[threadIdx.x];
    }
    __syncthreads();

    int tid = threadIdx.x;
    int sub = tid & (LPN - 1);
    int n = blockIdx.x * NPB + (tid >> LPNSH);   // all n < NNODES (6250*32 exact)

    int start = row_ptr[n];
    int end = (n == NNODES - 1) ? NEDGES : row_ptr[n + 1];

    float acc[WID];
#pragma unroll
    for (int k = 0; k < WID; k++) acc[k] = 0.0f;

    int p = start + sub;
    for (int c = 0; c < NCHK; c++) {
        int slim = (c + 1) << CHBITS;
        while (p < end) {
            float2 c2 = csr[p];
            int s = __float_as_int(c2.y);
            if (s >= slim) break;
            float w = c2.x;
            const float* hrow = hs + (size_t)s * HPAD;
            float4 a = *reinterpret_cast<const float4*>(hrow + 0);
            float4 b = *reinterpret_cast<const float4*>(hrow + 4);
            float2 cc = *reinterpret_cast<const float2*>(hrow + 8);
            acc[0] += w * a.x; acc[1] += w * a.y; acc[2] += w * a.z; acc[3] += w * a.w;
            acc[4] += w * b.x; acc[5] += w * b.y; acc[6] += w * b.z; acc[7] += w * b.w;
            acc[8] += w * cc.x; acc[9] += w * cc.y;
            p += LPN;
        }
        __syncthreads();   // phase barrier: whole block advances chunk together
    }
    // drain (should be empty: chunk 12 covers all src < 13*16384)
    for (; p < end; p += LPN) {
        float2 c2 = csr[p];
        float w = c2.x;
        int s = __float_as_int(c2.y);
        const float* hrow = hs + (size_t)s * HPAD;
        float4 a = *reinterpret_cast<const float4*>(hrow + 0);
        float4 b = *reinterpret_cast<const float4*>(hrow + 4);
        float2 cc = *reinterpret_cast<const float2*>(hrow + 8);
        acc[0] += w * a.x; acc[1] += w * a.y; acc[2] += w * a.z; acc[3] += w * a.w;
        acc[4] += w * b.x; acc[5] += w * b.y; acc[6] += w * b.z; acc[7] += w * b.w;
        acc[8] += w * cc.x; acc[9] += w * cc.y;
    }

    // butterfly reduce across the 8-lane group; every lane ends with the sum
#pragma unroll
    for (int m = 1; m < LPN; m <<= 1) {
#pragma unroll
        for (int k = 0; k < WID; k++) acc[k] += __shfl_xor(acc[k], m, 64);
    }

    float ii = inv_in[n];
    float dot = 0.0f;
#pragma unroll
    for (int j = 0; j < WID; j++) {
        float y = 0.0f;
#pragma unroll
        for (int k = 0; k < WID; k++) y += acc[k] * sW1[k * WID + j];
        y = y * ii + sb1[j];
        y = y > 0.0f ? y : 0.0f;
        dot += y * sW2[j];
    }
    if (sub == 0) sproj[n] = dot * inv_out[n];
}

// ---------------------------------------------------------------------------
// K8: pull-mode scalar aggregate of gconv2 FUSED with graph pooling.
// 8 lanes per node; segmented reduce starts at offset LPN (sorted gids).
// __shfl clamps OOR lanes to SELF on AMD -> keep the lane+off<64 guard.
// ---------------------------------------------------------------------------
__global__ void k_agg2_pool(const float2* __restrict__ csr,
                            const int* __restrict__ row_ptr,
                            const float* __restrict__ sproj,
                            const float* __restrict__ inv_in,
                            const float* __restrict__ b2,
                            const int* __restrict__ graph_ids,
                            float* __restrict__ pooled) {
    int tid = threadIdx.x;
    int lane = tid & 63;
    int sub = tid & (LPN - 1);
    int n = blockIdx.x * NPB + (tid >> LPNSH);   // all n < NNODES

    int start = row_ptr[n];
    int end = (n == NNODES - 1) ? NEDGES : row_ptr[n + 1];
    float sum = 0.0f;
    for (int p = start + sub; p < end; p += LPN) {
        float2 c2 = csr[p];
        sum += c2.x * sproj[__float_as_int(c2.y)];
    }
#pragma unroll
    for (int m = 1; m < LPN; m <<= 1) sum += __shfl_xor(sum, m, 64);

    float v = sum * inv_in[n] + b2[0];
    int g = graph_ids[n];

    // segmented suffix-run reduce over the 8 node slots of the wave
#pragma unroll
    for (int off = LPN; off < 64; off <<= 1) {
        float vv = __shfl_down(v, off, 64);
        int gg = __shfl_down(g, off, 64);
        if (lane + off < 64 && gg == g) v += vv;
    }
    int gprev = __shfl_up(g, LPN, 64);
    bool head = (sub == 0) && (lane < LPN || gprev != g);
    if (head) atomicAdd(&pooled[g], v);
}

// ---------------------------------------------------------------------------
// K9: out[g] = pooled[g] / count(g); counts via binary search on sorted gids
// ---------------------------------------------------------------------------
__global__ void k_final(const float* __restrict__ pooled,
                        const int* __restrict__ gids,
                        float* __restrict__ out) {
    int g = blockIdx.x * blockDim.x + threadIdx.x;
    if (g >= NGRAPHS) return;
    int lo = 0, hi = NNODES;
    while (lo < hi) { int m = (lo + hi) >> 1; if (gids[m] < g) lo = m + 1; else hi = m; }
    int first = lo;
    hi = NNODES;
    while (lo < hi) { int m = (lo + hi) >> 1; if (gids[m] < g + 1) lo = m + 1; else hi = m; }
    int cnt = lo - first;
    out[g] = pooled[g] / (float)(cnt > 0 ? cnt : 1);
}

// ---------------------------------------------------------------------------
extern "C" void kernel_launch(void* const* d_in, const int* in_sizes, int n_in,
                              void* d_out, int out_size, void* d_ws, size_t ws_size,
                              hipStream_t stream) {
    const float* atom = (const float*)d_in[0];
    const float* r    = (const float*)d_in[1];
    const float* Wemb = (const float*)d_in[2];
    const float* bemb = (const float*)d_in[3];
    const float* W1   = (const float*)d_in[4];
    const float* b1   = (const float*)d_in[5];
    const float* W2   = (const float*)d_in[6];
    const float* b2   = (const float*)d_in[7];
    const int*   src  = (const int*)d_in[8];
    const int*   dst  = (const int*)d_in[9];
    const int*   gids = (const int*)d_in[10];
    float* out = (float*)d_out;

    // Workspace layout (16B-aligned chunks), ~120 MB total.
    char* w = (char*)d_ws;
    float* pooled  = (float*)w;  w += (size_t)NGRAPHS * 4;          // zeroed (2 KB)
    int*   subw    = (int*)w;    w += (size_t)SUBW * 4;             // zeroed (6.4 KB)
    int*   cnt     = (int*)w;    w += (size_t)CNT_N * 4;            // 0.8 MB
    int*   partial = (int*)w;    w += (size_t)((SBLKS + 3) & ~3) * 4;
    int*   row_ptr = (int*)w;    w += (size_t)((NNODES + 4) & ~3) * 4;
    float* inv_in  = (float*)w;  w += (size_t)NNODES * 4;
    float* inv_out = (float*)w;  w += (size_t)NNODES * 4;
    float* sproj   = (float*)w;  w += (size_t)NNODES * 4;
    float* hs      = (float*)w;  w += (size_t)NNODES * HPAD * 4;    // 12.8 MB
    float2* dstpart = (float2*)w; w += (size_t)NEDGES * 8;          // 51.2 MB
    float2* csr     = (float2*)w; w += (size_t)NEDGES * 8;          // 51.2 MB
    // srcpart aliases csr: dead before k_bucket_csr writes csr
    unsigned short* srcpart = (unsigned short*)csr;                 // 12.8 MB view

    hipMemsetAsync(pooled, 0, (size_t)NGRAPHS * 4, stream);
    hipMemsetAsync(subw, 0, (size_t)SUBW * 4, stream);

    const int B = 256;

    k_part_count<<<PBLK, B, 0, stream>>>(src, dst, cnt, subw);
    k_scan_partial<<<SBLKS, B, 0, stream>>>(cnt, partial);
    k_scan_top<<<1, 1024, 0, stream>>>(partial);
    k_scan_apply<<<SBLKS, B, 0, stream>>>(cnt, partial);
    k_subscan<<<1, B, 0, stream>>>(subw);
    k_part_scatter<<<PBLK, B, 0, stream>>>(r, src, dst, cnt, dstpart, srcpart);
    k_bucket_odeg<<<NB, B, 0, stream>>>(srcpart, cnt, inv_out);   // before csr write (alias)
    k_bucket_csr<<<CSR_GRID, B, 0, stream>>>(dstpart, subw, csr, row_ptr, inv_in);
    k_embed<<<NBLK, B, 0, stream>>>(atom, Wemb, bemb, inv_out, hs);
    k_agg1<<<AGG_BLKS, B, 0, stream>>>(csr, row_ptr, hs, W1, b1, W2, inv_in, inv_out, sproj);
    k_agg2_pool<<<AGG_BLKS, B, 0, stream>>>(csr, row_ptr, sproj, inv_in, b2, gids, pooled);
    k_final<<<(NGRAPHS + B - 1) / B, B, 0, stream>>>(pooled, gids, out);
}

// Round 3
// 714.858 us; speedup vs baseline: 1.1852x; 1.1852x over previous
//
#include <hip/hip_runtime.h>
#include <math.h>

#define NNODES  200000
#define NEDGES  6400000
#define NGRAPHS 512
#define FIN     92
#define WID     10
#define HPAD    16                     // hs row padded to 16 floats (64 B)
#define NBLK    ((NNODES + 255) / 256) // 782

// partition geometry -- round-10: dst plane partitioned at SUB-BUCKET
// (128-node) granularity so the CSR build reads only its own range.
// Round-2 regression root-caused: 8 siblings filtering a shared parent
// range = 8x redundant reads (FETCH 50->103 MB, dur 127->247 us).
#define LBITS   10
#define LSIZE   1024                   // src-plane bucket (unchanged, for odeg)
#define LMASK   (LSIZE - 1)
#define NB      196                    // src-plane buckets
#define SUBSH   7
#define SUBN    128                    // dst nodes per sub-bucket
#define NSUB    1563                   // ceil(200000/128) dst sub-buckets
#define PBLK    512                    // partition blocks
#define EPB     (NEDGES / PBLK)        // 12500 edges per partition block (exact)
#define TILE    1250                   // staging tile (EPB = 10 * TILE exactly)
#define NTILE   (EPB / TILE)           // 10
#define CELLS   (NSUB + NB)            // 1759 (dst sub plane + src plane)
#define CNT_N   (CELLS * PBLK)         // 900,608 scan elements
#define SBLKS   (CNT_N / 256)          // 3518 scan blocks (exact)
#define CPT     7                      // dst cells per thread in tile scan (7*256>=1563)

// chunk-ordered rows (for k_agg1 gather locality)
#define CHBITS  14
#define NCHK    13                     // ceil(200000/16384) src chunks
#define SKEYS   (SUBN * NCHK)          // 1664 keys per sub-bucket
#define SKPAD   1792                   // 256*7 padded key array
#define SKPT    7                      // keys per thread in scan
#define SMAX    5120                   // LDS staging cap: mean 4096 + 16 sigma

// multi-lane aggregation (round-8): 8 lanes per node, butterfly reduce.
#define LPN     8
#define LPNSH   3
#define NPB     (256 / LPN)            // 32 nodes per block
#define AGG_BLKS (NNODES / NPB)        // 6250 (exact)

// ---------------------------------------------------------------------------
// P1: per-(cell,block) counts via LDS histograms. dst at sub-bucket
// granularity, src at 1024-bucket granularity. ZERO global atomics.
// ---------------------------------------------------------------------------
__global__ void k_part_count(const int* __restrict__ src,
                             const int* __restrict__ dst,
                             int* __restrict__ cnt) {
    __shared__ int hSub[NSUB];
    __shared__ int hS[NB];
    int tid = threadIdx.x, k = blockIdx.x;
    for (int i = tid; i < NSUB; i += 256) hSub[i] = 0;
    if (tid < NB) hS[tid] = 0;
    __syncthreads();
    int base = k * EPB;
    for (int i = tid; i < EPB; i += 256) {
        int e = base + i;
        atomicAdd(&hSub[dst[e] >> SUBSH], 1);
        atomicAdd(&hS[src[e] >> LBITS], 1);
    }
    __syncthreads();
    for (int i = tid; i < NSUB; i += 256) cnt[i * PBLK + k] = hSub[i];
    if (tid < NB) cnt[(NSUB + tid) * PBLK + k] = hS[tid];
}

// ---------------------------------------------------------------------------
// Scan step 1: per-block (256-elem) partial sums of cnt
// ---------------------------------------------------------------------------
__global__ void k_scan_partial(const int* __restrict__ cnt,
                               int* __restrict__ partial) {
    __shared__ int sdata[256];
    int tid = threadIdx.x;
    sdata[tid] = cnt[blockIdx.x * 256 + tid];
    __syncthreads();
    for (int s = 128; s > 0; s >>= 1) {
        if (tid < s) sdata[tid] += sdata[tid + s];
        __syncthreads();
    }
    if (tid == 0) partial[blockIdx.x] = sdata[0];
}

// ---------------------------------------------------------------------------
// Scan step 2: single-block exclusive scan of the 3518 partials
// ---------------------------------------------------------------------------
__global__ void k_scan_top(int* __restrict__ partial) {
    __shared__ int buf[1024];
    __shared__ int carry_s;
    if (threadIdx.x == 0) carry_s = 0;
    __syncthreads();
    for (int base = 0; base < SBLKS; base += 1024) {
        int i = base + threadIdx.x;
        int c = carry_s;
        int orig = (i < SBLKS) ? partial[i] : 0;
        buf[threadIdx.x] = orig;
        __syncthreads();
        for (int off = 1; off < 1024; off <<= 1) {
            int t = (threadIdx.x >= off) ? buf[threadIdx.x - off] : 0;
            __syncthreads();
            buf[threadIdx.x] += t;
            __syncthreads();
        }
        if (i < SBLKS) partial[i] = buf[threadIdx.x] - orig + c;
        __syncthreads();
        if (threadIdx.x == 0) carry_s = c + buf[1023];
        __syncthreads();
    }
}

// ---------------------------------------------------------------------------
// Scan step 3: apply -- in-place exclusive scan of cnt
// ---------------------------------------------------------------------------
__global__ void k_scan_apply(int* __restrict__ cnt,
                             const int* __restrict__ partial) {
    __shared__ int buf[256];
    int tid = threadIdx.x;
    int i = blockIdx.x * 256 + tid;
    int v = cnt[i];
    buf[tid] = v;
    __syncthreads();
    for (int off = 1; off < 256; off <<= 1) {
        int t = (tid >= off) ? buf[tid - off] : 0;
        __syncthreads();
        buf[tid] += t;
        __syncthreads();
    }
    cnt[i] = buf[tid] - v + partial[blockIdx.x];
}

// ---------------------------------------------------------------------------
// P2: TILE-STAGED scatter at sub-bucket granularity. Per 1250-edge tile:
// LDS hist -> LDS scan (1563 cells: 7/thread sequential + block scan) ->
// snapshot global cursors -> place records cell-ordered in LDS staging ->
// coalesced copy-out. ZERO global atomics.
// ---------------------------------------------------------------------------
__global__ void k_part_scatter(const float* __restrict__ r,
                               const int* __restrict__ src,
                               const int* __restrict__ dst,
                               const int* __restrict__ cnt,
                               float2* __restrict__ dstpart,
                               unsigned short* __restrict__ srcpart) {
    __shared__ int curD[NSUB], hD[NSUB], baseD[NSUB], segD[NSUB]; // 25,008 B
    __shared__ int curS[NB], hS[NB], baseS[NB], segS[NB];         //  3,136 B
    __shared__ int sbuf[256];
    __shared__ float2 stD[TILE];           // 10 KB staged dst records
    __shared__ int    ddD[TILE];           //  5 KB their global slots
    __shared__ unsigned short stS[TILE];   //2.5 KB staged src locals
    __shared__ int    ddS[TILE];           //  5 KB their global slots

    int tid = threadIdx.x, k = blockIdx.x;
    for (int i = tid; i < NSUB; i += 256) curD[i] = cnt[i * PBLK + k];
    if (tid < NB) curS[tid] = cnt[(NSUB + tid) * PBLK + k] - NEDGES;
    __syncthreads();

    int base = k * EPB;
    for (int t = 0; t < NTILE; t++) {
        int tbase = base + t * TILE;
        for (int i = tid; i < NSUB; i += 256) hD[i] = 0;
        if (tid < NB) hS[tid] = 0;
        __syncthreads();
        // pass A: tile histograms
        for (int i = tid; i < TILE; i += 256) {
            int e = tbase + i;
            atomicAdd(&hD[dst[e] >> SUBSH], 1);
            atomicAdd(&hS[src[e] >> LBITS], 1);
        }
        __syncthreads();
        // scan dst plane: 7 cells/thread sequential + 256-block scan
        int cb = tid * CPT;
        int vals[CPT];
        int sum = 0;
#pragma unroll
        for (int j = 0; j < CPT; j++) {
            int c = cb + j;
            int v = (c < NSUB) ? hD[c] : 0;
            vals[j] = v;
            sum += v;
        }
        sbuf[tid] = sum;
        __syncthreads();
        for (int off = 1; off < 256; off <<= 1) {
            int tv = (tid >= off) ? sbuf[tid - off] : 0;
            __syncthreads();
            sbuf[tid] += tv;
            __syncthreads();
        }
        int run = sbuf[tid] - sum;
#pragma unroll
        for (int j = 0; j < CPT; j++) {
            int c = cb + j;
            if (c < NSUB) {
                baseD[c] = run;
                segD[c] = curD[c];
                curD[c] += vals[j];
                hD[c] = run;           // reuse as tile cursor
                run += vals[j];
            }
        }
        __syncthreads();
        // scan src plane (196 cells, direct 256-block scan)
        int v2 = (tid < NB) ? hS[tid] : 0;
        sbuf[tid] = v2;
        __syncthreads();
        for (int off = 1; off < 256; off <<= 1) {
            int tv = (tid >= off) ? sbuf[tid - off] : 0;
            __syncthreads();
            sbuf[tid] += tv;
            __syncthreads();
        }
        if (tid < NB) {
            baseS[tid] = sbuf[tid] - v2;
            segS[tid] = curS[tid];
            curS[tid] += v2;
            hS[tid] = baseS[tid];
        }
        __syncthreads();
        // pass B: stage records cell-ordered, precompute global destinations
        for (int i = tid; i < TILE; i += 256) {
            int e = tbase + i;
            int s = src[e], d = dst[e];
            float x = r[3 * e + 0];
            float y = r[3 * e + 1];
            float z = r[3 * e + 2];
            float w = expf(-(x * x + y * y + z * z));
            int cd = d >> SUBSH;
            int idx = atomicAdd(&hD[cd], 1);
            stD[idx] = make_float2(w, __int_as_float((s << LBITS) | (d & LMASK)));
            ddD[idx] = segD[cd] + (idx - baseD[cd]);
            int cs = s >> LBITS;
            int ids = atomicAdd(&hS[cs], 1);
            stS[ids] = (unsigned short)(s & LMASK);
            ddS[ids] = segS[cs] + (ids - baseS[cs]);
        }
        __syncthreads();
        // pass C: coalesced copy-out
        for (int i = tid; i < TILE; i += 256) {
            dstpart[ddD[i]] = stD[i];
            srcpart[ddS[i]] = stS[i];
        }
        __syncthreads();
    }
}

// ---------------------------------------------------------------------------
// P3s: per-bucket out-degree histogram (LDS) -> inv_sqrt_out.
// Runs BEFORE k_bucket_csr because srcpart aliases the csr region.
// ---------------------------------------------------------------------------
__global__ void k_bucket_odeg(const unsigned short* __restrict__ srcpart,
                              const int* __restrict__ cnt,
                              float* __restrict__ inv_out) {
    __shared__ int hist[LSIZE];
    int tid = threadIdx.x, b = blockIdx.x;
    int bstart = cnt[(NSUB + b) * PBLK] - NEDGES;
    int bend = (b == NB - 1) ? NEDGES : (cnt[(NSUB + b + 1) * PBLK] - NEDGES);
    for (int l = tid; l < LSIZE; l += 256) hist[l] = 0;
    __syncthreads();
    for (int p = bstart + tid; p < bend; p += 256)
        atomicAdd(&hist[srcpart[p]], 1);
    __syncthreads();
    for (int l = tid; l < LSIZE; l += 256) {
        int n = (b << LBITS) + l;
        if (n < NNODES) {
            int c = hist[l];
            inv_out[n] = rsqrtf((float)(c < 1 ? 1 : c));
        }
    }
}

// ---------------------------------------------------------------------------
// P3d round-10: one block per sub-bucket reads ONLY its own ~4096-record
// range (coalesced, once per pass), counting-sorts by joint key
// (local7 * 13 + srcChunk), stages in LDS, writes csr COALESCED.
// ---------------------------------------------------------------------------
__global__ void k_bucket_csr(const float2* __restrict__ dstpart,
                             const int* __restrict__ cnt,
                             float2* __restrict__ csr,
                             int* __restrict__ row_ptr,
                             float* __restrict__ inv_in) {
    __shared__ int hist[SKPAD];      //  7,168 B
    __shared__ int sbuf[256];        //  1,024 B
    __shared__ float2 stout[SMAX];   // 40,960 B
    int tid = threadIdx.x;
    int sub = blockIdx.x;
    int substart = cnt[sub * PBLK];
    // for sub == NSUB-1 this reads the first src-plane cell == NEDGES
    int subend = cnt[(sub + 1) * PBLK];
    int sz = subend - substart;

    for (int j = tid; j < SKPAD; j += 256) hist[j] = 0;
    __syncthreads();
    // count keys over own range only
    for (int p = substart + tid; p < subend; p += 256) {
        unsigned pk = __float_as_uint(dstpart[p].y);
        atomicAdd(&hist[(pk & 127u) * NCHK + (pk >> 24)], 1);
    }
    __syncthreads();
    // exclusive scan over the 1792 (padded) keys
    int kb = tid * SKPT;
    int sum = 0;
#pragma unroll
    for (int j = 0; j < SKPT; j++) sum += hist[kb + j];
    sbuf[tid] = sum;
    __syncthreads();
    for (int off = 1; off < 256; off <<= 1) {
        int tv = (tid >= off) ? sbuf[tid - off] : 0;
        __syncthreads();
        sbuf[tid] += tv;
        __syncthreads();
    }
    int run = sbuf[tid] - sum + substart;   // global cursor for own keys
#pragma unroll
    for (int j = 0; j < SKPT; j++) {
        int c = hist[kb + j];
        hist[kb + j] = run;
        run += c;
    }
    __syncthreads();
    // rows: start = cursor at key l*NCHK (read BEFORE placement mutates)
    if (tid < SUBN) {
        int l = tid;
        int rs = hist[l * NCHK];
        int re = (l == SUBN - 1) ? subend : hist[(l + 1) * NCHK];
        int n = (sub << SUBSH) + l;
        if (n < NNODES) {
            row_ptr[n] = rs;
            int c = re - rs;
            inv_in[n] = rsqrtf((float)(c < 1 ? 1 : c));
        }
    }
    __syncthreads();
    // placement
    if (sz <= SMAX) {
        for (int p = substart + tid; p < subend; p += 256) {
            float2 rec = dstpart[p];
            unsigned pk = __float_as_uint(rec.y);
            int pos = atomicAdd(&hist[(pk & 127u) * NCHK + (pk >> 24)], 1);
            stout[pos - substart] = make_float2(rec.x, __int_as_float((int)(pk >> LBITS)));
        }
        __syncthreads();
        // coalesced copy-out
        for (int i = tid; i < sz; i += 256)
            csr[substart + i] = stout[i];
    } else {
        // overflow fallback (statistically unreachable: SMAX = mean + 16 sigma)
        for (int p = substart + tid; p < subend; p += 256) {
            float2 rec = dstpart[p];
            unsigned pk = __float_as_uint(rec.y);
            int pos = atomicAdd(&hist[(pk & 127u) * NCHK + (pk >> 24)], 1);
            csr[pos] = make_float2(rec.x, __int_as_float((int)(pk >> LBITS)));
        }
    }
}

// ---------------------------------------------------------------------------
// K5: hs[n,:] = (A[n,:] @ W_emb + b_emb) * inv_sqrt_out[n], padded rows
// ---------------------------------------------------------------------------
__global__ void k_embed(const float* __restrict__ A,
                        const float* __restrict__ Wemb,
                        const float* __restrict__ bemb,
                        const float* __restrict__ inv_out,
                        float* __restrict__ hs) {
    __shared__ float sW[FIN * WID];
    __shared__ float sb[WID];
    for (int i = threadIdx.x; i < FIN * WID; i += blockDim.x) sW[i] = Wemb[i];
    if (threadIdx.x < WID) sb[threadIdx.x] = bemb[threadIdx.x];
    __syncthreads();

    int n = blockIdx.x * blockDim.x + threadIdx.x;
    if (n >= NNODES) return;

    float acc[WID];
#pragma unroll
    for (int k = 0; k < WID; k++) acc[k] = sb[k];

    const float4* row4 = reinterpret_cast<const float4*>(A + (size_t)n * FIN);
#pragma unroll
    for (int f4 = 0; f4 < FIN / 4; f4++) {
        float4 v = row4[f4];
        int f = f4 * 4;
#pragma unroll
        for (int k = 0; k < WID; k++) acc[k] += v.x * sW[(f + 0) * WID + k];
#pragma unroll
        for (int k = 0; k < WID; k++) acc[k] += v.y * sW[(f + 1) * WID + k];
#pragma unroll
        for (int k = 0; k < WID; k++) acc[k] += v.z * sW[(f + 2) * WID + k];
#pragma unroll
        for (int k = 0; k < WID; k++) acc[k] += v.w * sW[(f + 3) * WID + k];
    }

    float sc = inv_out[n];
    float* out = hs + (size_t)n * HPAD;
    float4 o0 = make_float4(acc[0] * sc, acc[1] * sc, acc[2] * sc, acc[3] * sc);
    float4 o1 = make_float4(acc[4] * sc, acc[5] * sc, acc[6] * sc, acc[7] * sc);
    float2 o2 = make_float2(acc[8] * sc, acc[9] * sc);
    *reinterpret_cast<float4*>(out + 0) = o0;
    *reinterpret_cast<float4*>(out + 4) = o1;
    *reinterpret_cast<float2*>(out + 8) = o2;
}

// ---------------------------------------------------------------------------
// K7: pull-mode aggregate of gconv1 FUSED with node update + gconv2 proj.
// 8 lanes per node (round-8), phase-locked chunk walk, butterfly reduce.
// ---------------------------------------------------------------------------
__global__ void k_agg1(const float2* __restrict__ csr,
                       const int* __restrict__ row_ptr,
                       const float* __restrict__ hs,
                       const float* __restrict__ W1,
                       const float* __restrict__ b1,
                       const float* __restrict__ W2,
                       const float* __restrict__ inv_in,
                       const float* __restrict__ inv_out,
                       float* __restrict__ sproj) {
    __shared__ float sW1[WID * WID];
    __shared__ float sb1[WID];
    __shared__ float sW2[WID];
    for (int i = threadIdx.x; i < WID * WID; i += blockDim.x) sW1[i] = W1[i];
    if (threadIdx.x < WID) {
        sb1[threadIdx.x] = b1[threadIdx.x];
        sW2[threadIdx.x] = W2[threadIdx.x];
    }
    __syncthreads();

    int tid = threadIdx.x;
    int sub = tid & (LPN - 1);
    int n = blockIdx.x * NPB + (tid >> LPNSH);   // all n < NNODES (6250*32 exact)

    int start = row_ptr[n];
    int end = (n == NNODES - 1) ? NEDGES : row_ptr[n + 1];

    float acc[WID];
#pragma unroll
    for (int k = 0; k < WID; k++) acc[k] = 0.0f;

    int p = start + sub;
    for (int c = 0; c < NCHK; c++) {
        int slim = (c + 1) << CHBITS;
        while (p < end) {
            float2 c2 = csr[p];
            int s = __float_as_int(c2.y);
            if (s >= slim) break;
            float w = c2.x;
            const float* hrow = hs + (size_t)s * HPAD;
            float4 a = *reinterpret_cast<const float4*>(hrow + 0);
            float4 b = *reinterpret_cast<const float4*>(hrow + 4);
            float2 cc = *reinterpret_cast<const float2*>(hrow + 8);
            acc[0] += w * a.x; acc[1] += w * a.y; acc[2] += w * a.z; acc[3] += w * a.w;
            acc[4] += w * b.x; acc[5] += w * b.y; acc[6] += w * b.z; acc[7] += w * b.w;
            acc[8] += w * cc.x; acc[9] += w * cc.y;
            p += LPN;
        }
        __syncthreads();   // phase barrier: whole block advances chunk together
    }
    // drain (should be empty: chunk 12 covers all src < 13*16384)
    for (; p < end; p += LPN) {
        float2 c2 = csr[p];
        float w = c2.x;
        int s = __float_as_int(c2.y);
        const float* hrow = hs + (size_t)s * HPAD;
        float4 a = *reinterpret_cast<const float4*>(hrow + 0);
        float4 b = *reinterpret_cast<const float4*>(hrow + 4);
        float2 cc = *reinterpret_cast<const float2*>(hrow + 8);
        acc[0] += w * a.x; acc[1] += w * a.y; acc[2] += w * a.z; acc[3] += w * a.w;
        acc[4] += w * b.x; acc[5] += w * b.y; acc[6] += w * b.z; acc[7] += w * b.w;
        acc[8] += w * cc.x; acc[9] += w * cc.y;
    }

    // butterfly reduce across the 8-lane group; every lane ends with the sum
#pragma unroll
    for (int m = 1; m < LPN; m <<= 1) {
#pragma unroll
        for (int k = 0; k < WID; k++) acc[k] += __shfl_xor(acc[k], m, 64);
    }

    float ii = inv_in[n];
    float dot = 0.0f;
#pragma unroll
    for (int j = 0; j < WID; j++) {
        float y = 0.0f;
#pragma unroll
        for (int k = 0; k < WID; k++) y += acc[k] * sW1[k * WID + j];
        y = y * ii + sb1[j];
        y = y > 0.0f ? y : 0.0f;
        dot += y * sW2[j];
    }
    if (sub == 0) sproj[n] = dot * inv_out[n];
}

// ---------------------------------------------------------------------------
// K8: pull-mode scalar aggregate of gconv2 FUSED with graph pooling.
// 8 lanes per node; segmented reduce starts at offset LPN (sorted gids).
// __shfl clamps OOR lanes to SELF on AMD -> keep the lane+off<64 guard.
// ---------------------------------------------------------------------------
__global__ void k_agg2_pool(const float2* __restrict__ csr,
                            const int* __restrict__ row_ptr,
                            const float* __restrict__ sproj,
                            const float* __restrict__ inv_in,
                            const float* __restrict__ b2,
                            const int* __restrict__ graph_ids,
                            float* __restrict__ pooled) {
    int tid = threadIdx.x;
    int lane = tid & 63;
    int sub = tid & (LPN - 1);
    int n = blockIdx.x * NPB + (tid >> LPNSH);   // all n < NNODES

    int start = row_ptr[n];
    int end = (n == NNODES - 1) ? NEDGES : row_ptr[n + 1];
    float sum = 0.0f;
    for (int p = start + sub; p < end; p += LPN) {
        float2 c2 = csr[p];
        sum += c2.x * sproj[__float_as_int(c2.y)];
    }
#pragma unroll
    for (int m = 1; m < LPN; m <<= 1) sum += __shfl_xor(sum, m, 64);

    float v = sum * inv_in[n] + b2[0];
    int g = graph_ids[n];

    // segmented suffix-run reduce over the 8 node slots of the wave
#pragma unroll
    for (int off = LPN; off < 64; off <<= 1) {
        float vv = __shfl_down(v, off, 64);
        int gg = __shfl_down(g, off, 64);
        if (lane + off < 64 && gg == g) v += vv;
    }
    int gprev = __shfl_up(g, LPN, 64);
    bool head = (sub == 0) && (lane < LPN || gprev != g);
    if (head) atomicAdd(&pooled[g], v);
}

// ---------------------------------------------------------------------------
// K9: out[g] = pooled[g] / count(g); counts via binary search on sorted gids
// ---------------------------------------------------------------------------
__global__ void k_final(const float* __restrict__ pooled,
                        const int* __restrict__ gids,
                        float* __restrict__ out) {
    int g = blockIdx.x * blockDim.x + threadIdx.x;
    if (g >= NGRAPHS) return;
    int lo = 0, hi = NNODES;
    while (lo < hi) { int m = (lo + hi) >> 1; if (gids[m] < g) lo = m + 1; else hi = m; }
    int first = lo;
    hi = NNODES;
    while (lo < hi) { int m = (lo + hi) >> 1; if (gids[m] < g + 1) lo = m + 1; else hi = m; }
    int cnt = lo - first;
    out[g] = pooled[g] / (float)(cnt > 0 ? cnt : 1);
}

// ---------------------------------------------------------------------------
extern "C" void kernel_launch(void* const* d_in, const int* in_sizes, int n_in,
                              void* d_out, int out_size, void* d_ws, size_t ws_size,
                              hipStream_t stream) {
    const float* atom = (const float*)d_in[0];
    const float* r    = (const float*)d_in[1];
    const float* Wemb = (const float*)d_in[2];
    const float* bemb = (const float*)d_in[3];
    const float* W1   = (const float*)d_in[4];
    const float* b1   = (const float*)d_in[5];
    const float* W2   = (const float*)d_in[6];
    const float* b2   = (const float*)d_in[7];
    const int*   src  = (const int*)d_in[8];
    const int*   dst  = (const int*)d_in[9];
    const int*   gids = (const int*)d_in[10];
    float* out = (float*)d_out;

    // Workspace layout (16B-aligned chunks), ~123 MB total.
    char* w = (char*)d_ws;
    float* pooled  = (float*)w;  w += (size_t)NGRAPHS * 4;          // zeroed (2 KB)
    int*   cnt     = (int*)w;    w += (size_t)CNT_N * 4;            // 3.6 MB
    int*   partial = (int*)w;    w += (size_t)((SBLKS + 3) & ~3) * 4;
    int*   row_ptr = (int*)w;    w += (size_t)((NNODES + 4) & ~3) * 4;
    float* inv_in  = (float*)w;  w += (size_t)NNODES * 4;
    float* inv_out = (float*)w;  w += (size_t)NNODES * 4;
    float* sproj   = (float*)w;  w += (size_t)NNODES * 4;
    float* hs      = (float*)w;  w += (size_t)NNODES * HPAD * 4;    // 12.8 MB
    float2* dstpart = (float2*)w; w += (size_t)NEDGES * 8;          // 51.2 MB
    float2* csr     = (float2*)w; w += (size_t)NEDGES * 8;          // 51.2 MB
    // srcpart aliases csr: dead before k_bucket_csr writes csr
    unsigned short* srcpart = (unsigned short*)csr;                 // 12.8 MB view

    hipMemsetAsync(pooled, 0, (size_t)NGRAPHS * 4, stream);

    const int B = 256;

    k_part_count<<<PBLK, B, 0, stream>>>(src, dst, cnt);
    k_scan_partial<<<SBLKS, B, 0, stream>>>(cnt, partial);
    k_scan_top<<<1, 1024, 0, stream>>>(partial);
    k_scan_apply<<<SBLKS, B, 0, stream>>>(cnt, partial);
    k_part_scatter<<<PBLK, B, 0, stream>>>(r, src, dst, cnt, dstpart, srcpart);
    k_bucket_odeg<<<NB, B, 0, stream>>>(srcpart, cnt, inv_out);   // before csr write (alias)
    k_bucket_csr<<<NSUB, B, 0, stream>>>(dstpart, cnt, csr, row_ptr, inv_in);
    k_embed<<<NBLK, B, 0, stream>>>(atom, Wemb, bemb, inv_out, hs);
    k_agg1<<<AGG_BLKS, B, 0, stream>>>(csr, row_ptr, hs, W1, b1, W2, inv_in, inv_out, sproj);
    k_agg2_pool<<<AGG_BLKS, B, 0, stream>>>(csr, row_ptr, sproj, inv_in, b2, gids, pooled);
    k_final<<<(NGRAPHS + B - 1) / B, B, 0, stream>>>(pooled, gids, out);
}

// Round 4
// 667.954 us; speedup vs baseline: 1.2685x; 1.0702x over previous
//
#include <hip/hip_runtime.h>
#include <math.h>

#define NNODES  200000
#define NEDGES  6400000
#define NGRAPHS 512
#define FIN     92
#define WID     10
#define HPAD    16                     // hs row padded to 16 floats (64 B)
#define NBLK    ((NNODES + 255) / 256) // 782

// partition geometry -- round-11: two-phase radix partition.
// Phase 1 (scatter): coarse 1024-node buckets, runs ~6.4 recs -> low amp.
// Phase 2 (refine): 8-way ballot-multisplit to 128-node sub-buckets,
// ascending streams -> amp ~1. Round-3's one-pass fine scatter had 0.8
// recs/cell/tile -> WRITE 195 MB, 189 us.
#define LBITS   10
#define LSIZE   1024                   // coarse bucket (both planes)
#define LMASK   (LSIZE - 1)
#define NB      196                    // coarse buckets
#define SUBSH   7
#define SUBN    128                    // dst nodes per sub-bucket
#define NSUB    1563                   // ceil(200000/128) dst sub-buckets
#define NSUBP   1608                   // padded alloc (incl sentinel)
#define PBLK    1024                   // partition blocks (round-11: 2x for occupancy)
#define EPB     (NEDGES / PBLK)        // 6250 edges per partition block (exact)
#define TILE    1250                   // staging tile (EPB = 5 * TILE exactly)
#define NTILE   (EPB / TILE)           // 5
#define CELLS   (2 * NB)               // 392 (dst plane + src plane)
#define CNT_N   (CELLS * PBLK)         // 401,408 scan elements
#define SBLKS   (CNT_N / 256)          // 1568 scan blocks (exact)
#define REF_GRID (NB * 8)              // 1568 refine blocks (8 per parent)

// chunk-ordered rows (for k_agg1 gather locality)
#define CHBITS  14
#define NCHK    13                     // ceil(200000/16384) src chunks
#define SKEYS   (SUBN * NCHK)          // 1664 keys per sub-bucket
#define SKPAD   1792                   // 256*7 padded key array
#define SKPT    7                      // keys per thread in scan
#define SMAX    5120                   // LDS staging cap: mean 4096 + 16 sigma

// multi-lane aggregation (round-8): 8 lanes per node, butterfly reduce.
#define LPN     8
#define LPNSH   3
#define NPB     (256 / LPN)            // 32 nodes per block
#define AGG_BLKS (NNODES / NPB)        // 6250 (exact)

// ---------------------------------------------------------------------------
// P1: per-(bucket,block) counts via LDS histograms; dst histogrammed at
// sub-bucket granularity then summed 8-way (cnt values = coarse), sub totals
// accumulated into global subcnt (round-2-proven). ZERO hot-path atomics.
// ---------------------------------------------------------------------------
__global__ void k_part_count(const int* __restrict__ src,
                             const int* __restrict__ dst,
                             int* __restrict__ cnt,
                             int* __restrict__ subcnt) {
    __shared__ int hSub[NSUB];
    __shared__ int hS[NB];
    int tid = threadIdx.x, k = blockIdx.x;
    for (int i = tid; i < NSUB; i += 256) hSub[i] = 0;
    if (tid < NB) hS[tid] = 0;
    __syncthreads();
    int base = k * EPB;
    for (int i = tid; i < EPB; i += 256) {
        int e = base + i;
        atomicAdd(&hSub[dst[e] >> SUBSH], 1);
        atomicAdd(&hS[src[e] >> LBITS], 1);
    }
    __syncthreads();
    if (tid < NB) {
        int s = 0;
        int b0 = tid * 8;
#pragma unroll
        for (int j = 0; j < 8; j++) {
            int ix = b0 + j;
            if (ix < NSUB) s += hSub[ix];
        }
        cnt[tid * PBLK + k] = s;
        cnt[(NB + tid) * PBLK + k] = hS[tid];
    }
    for (int i = tid; i < NSUB; i += 256) {
        int v = hSub[i];
        if (v) atomicAdd(&subcnt[i], v);
    }
}

// ---------------------------------------------------------------------------
// Scan step 1: per-block (256-elem) partial sums of cnt
// ---------------------------------------------------------------------------
__global__ void k_scan_partial(const int* __restrict__ cnt,
                               int* __restrict__ partial) {
    __shared__ int sdata[256];
    int tid = threadIdx.x;
    sdata[tid] = cnt[blockIdx.x * 256 + tid];
    __syncthreads();
    for (int s = 128; s > 0; s >>= 1) {
        if (tid < s) sdata[tid] += sdata[tid + s];
        __syncthreads();
    }
    if (tid == 0) partial[blockIdx.x] = sdata[0];
}

// ---------------------------------------------------------------------------
// Scan step 2: single-block exclusive scan of the 1568 partials
// ---------------------------------------------------------------------------
__global__ void k_scan_top(int* __restrict__ partial) {
    __shared__ int buf[1024];
    __shared__ int carry_s;
    if (threadIdx.x == 0) carry_s = 0;
    __syncthreads();
    for (int base = 0; base < SBLKS; base += 1024) {
        int i = base + threadIdx.x;
        int c = carry_s;
        int orig = (i < SBLKS) ? partial[i] : 0;
        buf[threadIdx.x] = orig;
        __syncthreads();
        for (int off = 1; off < 1024; off <<= 1) {
            int t = (threadIdx.x >= off) ? buf[threadIdx.x - off] : 0;
            __syncthreads();
            buf[threadIdx.x] += t;
            __syncthreads();
        }
        if (i < SBLKS) partial[i] = buf[threadIdx.x] - orig + c;
        __syncthreads();
        if (threadIdx.x == 0) carry_s = c + buf[1023];
        __syncthreads();
    }
}

// ---------------------------------------------------------------------------
// Scan step 3: apply -- in-place exclusive scan of cnt
// ---------------------------------------------------------------------------
__global__ void k_scan_apply(int* __restrict__ cnt,
                             const int* __restrict__ partial) {
    __shared__ int buf[256];
    int tid = threadIdx.x;
    int i = blockIdx.x * 256 + tid;
    int v = cnt[i];
    buf[tid] = v;
    __syncthreads();
    for (int off = 1; off < 256; off <<= 1) {
        int t = (tid >= off) ? buf[tid - off] : 0;
        __syncthreads();
        buf[tid] += t;
        __syncthreads();
    }
    cnt[i] = buf[tid] - v + partial[blockIdx.x];
}

// ---------------------------------------------------------------------------
// Round-11: exclusive scan of sub-bucket counts -> absolute csr sub starts
// (valid because csr order is ascending dst). Mirrors into subcur (the
// refine kernel's atomic cursors) so subscan stays clean for the csr build.
// ---------------------------------------------------------------------------
__global__ void k_subscan(int* __restrict__ subcnt,
                          int* __restrict__ subcur) {
    __shared__ int sbuf[256];
    int tid = threadIdx.x;
    int vals[SKPT];
    int sum = 0;
#pragma unroll
    for (int j = 0; j < SKPT; j++) {
        int c = tid * SKPT + j;
        int v = (c < NSUB) ? subcnt[c] : 0;
        vals[j] = v;
        sum += v;
    }
    sbuf[tid] = sum;
    __syncthreads();
    for (int off = 1; off < 256; off <<= 1) {
        int t = (tid >= off) ? sbuf[tid - off] : 0;
        __syncthreads();
        sbuf[tid] += t;
        __syncthreads();
    }
    int run = sbuf[tid] - sum;
#pragma unroll
    for (int j = 0; j < SKPT; j++) {
        int c = tid * SKPT + j;
        if (c < NSUB) {
            subcnt[c] = run;
            subcur[c] = run;
            run += vals[j];
        }
    }
    if (tid == 0) subcnt[NSUB] = NEDGES;
}

// ---------------------------------------------------------------------------
// P2: TILE-STAGED coarse scatter (round-1-proven structure; round-11:
// PBLK=1024/TILE=1250 halves LDS to ~30 KB -> 4 blocks/CU).
// ---------------------------------------------------------------------------
__global__ void k_part_scatter(const float* __restrict__ r,
                               const int* __restrict__ src,
                               const int* __restrict__ dst,
                               const int* __restrict__ cnt,
                               float2* __restrict__ dstpart,
                               unsigned short* __restrict__ srcpart) {
    __shared__ int curD[NB], curS[NB];     // running global cursors
    __shared__ int hD[NB], hS[NB];         // tile hist, then tile cursor
    __shared__ int baseD[NB], baseS[NB];   // tile-local exclusive base
    __shared__ int segD[NB], segS[NB];     // global cursor snapshot at tile start
    __shared__ int sbuf[256];
    __shared__ float2 stD[TILE];           // 10 KB staged dst records
    __shared__ int    ddD[TILE];           //  5 KB their global slots
    __shared__ unsigned short stS[TILE];   //2.5 KB staged src locals
    __shared__ int    ddS[TILE];           //  5 KB their global slots

    int tid = threadIdx.x, k = blockIdx.x;
    if (tid < NB) {
        curD[tid] = cnt[tid * PBLK + k];
        curS[tid] = cnt[(NB + tid) * PBLK + k] - NEDGES;
    }
    __syncthreads();

    int base = k * EPB;
    for (int t = 0; t < NTILE; t++) {
        int tbase = base + t * TILE;
        if (tid < NB) { hD[tid] = 0; hS[tid] = 0; }
        __syncthreads();
        // pass A: tile histograms
        for (int i = tid; i < TILE; i += 256) {
            int e = tbase + i;
            atomicAdd(&hD[dst[e] >> LBITS], 1);
            atomicAdd(&hS[src[e] >> LBITS], 1);
        }
        __syncthreads();
        // scan hD -> baseD; snapshot/advance global cursors
        int v = (tid < NB) ? hD[tid] : 0;
        sbuf[tid] = v;
        __syncthreads();
        for (int off = 1; off < 256; off <<= 1) {
            int tv = (tid >= off) ? sbuf[tid - off] : 0;
            __syncthreads();
            sbuf[tid] += tv;
            __syncthreads();
        }
        if (tid < NB) { baseD[tid] = sbuf[tid] - v; segD[tid] = curD[tid]; }
        __syncthreads();
        int v2 = (tid < NB) ? hS[tid] : 0;
        sbuf[tid] = v2;
        __syncthreads();
        for (int off = 1; off < 256; off <<= 1) {
            int tv = (tid >= off) ? sbuf[tid - off] : 0;
            __syncthreads();
            sbuf[tid] += tv;
            __syncthreads();
        }
        if (tid < NB) {
            baseS[tid] = sbuf[tid] - v2;
            segS[tid] = curS[tid];
            curD[tid] += hD[tid];
            curS[tid] += hS[tid];
            hD[tid] = baseD[tid];   // reuse as tile cursor
            hS[tid] = baseS[tid];
        }
        __syncthreads();
        // pass B: stage records cell-ordered, precompute global destinations
        for (int i = tid; i < TILE; i += 256) {
            int e = tbase + i;
            int s = src[e], d = dst[e];
            float x = r[3 * e + 0];
            float y = r[3 * e + 1];
            float z = r[3 * e + 2];
            float w = expf(-(x * x + y * y + z * z));
            int cd = d >> LBITS;
            int idx = atomicAdd(&hD[cd], 1);
            stD[idx] = make_float2(w, __int_as_float((s << LBITS) | (d & LMASK)));
            ddD[idx] = segD[cd] + (idx - baseD[cd]);
            int cs = s >> LBITS;
            int ids = atomicAdd(&hS[cs], 1);
            stS[ids] = (unsigned short)(s & LMASK);
            ddS[ids] = segS[cs] + (ids - baseS[cs]);
        }
        __syncthreads();
        // pass C: coalesced copy-out
        for (int i = tid; i < TILE; i += 256) {
            dstpart[ddD[i]] = stD[i];
            srcpart[ddS[i]] = stS[i];
        }
        __syncthreads();
    }
}

// ---------------------------------------------------------------------------
// P3s: per-bucket out-degree histogram (LDS) -> inv_sqrt_out.
// Runs BEFORE k_refine because srcpart aliases the csr/dstfine region.
// ---------------------------------------------------------------------------
__global__ void k_bucket_odeg(const unsigned short* __restrict__ srcpart,
                              const int* __restrict__ cnt,
                              float* __restrict__ inv_out) {
    __shared__ int hist[LSIZE];
    int tid = threadIdx.x, b = blockIdx.x;
    int bstart = cnt[(NB + b) * PBLK] - NEDGES;
    int bend = (b == NB - 1) ? NEDGES : (cnt[(NB + b + 1) * PBLK] - NEDGES);
    for (int l = tid; l < LSIZE; l += 256) hist[l] = 0;
    __syncthreads();
    for (int p = bstart + tid; p < bend; p += 256)
        atomicAdd(&hist[srcpart[p]], 1);
    __syncthreads();
    for (int l = tid; l < LSIZE; l += 256) {
        int n = (b << LBITS) + l;
        if (n < NNODES) {
            int c = hist[l];
            inv_out[n] = rsqrtf((float)(c < 1 ? 1 : c));
        }
    }
}

// ---------------------------------------------------------------------------
// Round-11 NEW: 8-way refine, coarse bucket -> 128-node sub-buckets.
// 8 blocks per parent, each streams its eighth once (coalesced reads).
// Per 64-record window: 3-ballot multisplit -> per-sub mask M, rank =
// popc(M below lane), leader does ONE global atomicAdd on the sub cursor,
// broadcast via shfl. Writes are 8 ascending streams/wave -> open lines
// complete in L2 -> write amp ~1. Order within a sub is irrelevant (the
// csr build counting-sorts by (local,chunk) anyway).
// ---------------------------------------------------------------------------
__global__ void k_refine(const float2* __restrict__ dstpart,
                         const int* __restrict__ cnt,
                         int* __restrict__ subcur,
                         float2* __restrict__ dstfine) {
    int p = blockIdx.x >> 3;          // parent bucket
    int q = blockIdx.x & 7;           // eighth of its range
    int bstart = cnt[p * PBLK];
    int bend = (p == NB - 1) ? NEDGES : cnt[(p + 1) * PBLK];
    int sz = bend - bstart;
    int qs = bstart + (int)(((long long)sz * q) >> 3);
    int qe = bstart + (int)(((long long)sz * (q + 1)) >> 3);
    int lane = threadIdx.x & 63;
    int wv = threadIdx.x >> 6;        // 4 waves per block

    for (int base = qs + wv * 64; base < qe; base += 256) {
        int i = base + lane;
        bool act = (i < qe);
        float2 rec = make_float2(0.0f, 0.0f);
        if (act) rec = dstpart[i];
        unsigned pk = __float_as_uint(rec.y);
        int s3 = (pk >> SUBSH) & 7;   // sub index within parent
        unsigned long long b0 = __ballot(s3 & 1);
        unsigned long long b1 = __ballot(s3 & 2);
        unsigned long long b2 = __ballot(s3 & 4);
        unsigned long long am = __ballot(act);
        unsigned long long M = ((s3 & 1) ? b0 : ~b0)
                             & ((s3 & 2) ? b1 : ~b1)
                             & ((s3 & 4) ? b2 : ~b2) & am;
        if (act) {
            int cj = __popcll(M);
            int rank = __popcll(M & ((1ull << lane) - 1ull));
            int leader = __ffsll((unsigned long long)M) - 1;
            int gb = 0;
            if (lane == leader) gb = atomicAdd(&subcur[p * 8 + s3], cj);
            gb = __shfl(gb, leader, 64);
            dstfine[gb + rank] = rec;
        }
    }
}

// ---------------------------------------------------------------------------
// P3d: per-sub-bucket CSR build (round-3-proven). Reads its own ~4096-record
// range, counting-sorts by (local7 * 13 + srcChunk), stages in LDS, writes
// COALESCED. Round-11: IN PLACE (data==output buffer): all reads of the
// block's own range complete (barrier) before the copy-out writes it;
// ranges are disjoint across blocks.
// ---------------------------------------------------------------------------
__global__ void k_bucket_csr(float2* __restrict__ data,
                             const int* __restrict__ subscan,
                             int* __restrict__ row_ptr,
                             float* __restrict__ inv_in) {
    __shared__ int hist[SKPAD];      //  7,168 B
    __shared__ int sbuf[256];        //  1,024 B
    __shared__ float2 stout[SMAX];   // 40,960 B
    int tid = threadIdx.x;
    int sub = blockIdx.x;
    int substart = subscan[sub];
    int subend = subscan[sub + 1];
    int sz = subend - substart;

    for (int j = tid; j < SKPAD; j += 256) hist[j] = 0;
    __syncthreads();
    // count keys over own range only
    for (int p = substart + tid; p < subend; p += 256) {
        unsigned pk = __float_as_uint(data[p].y);
        atomicAdd(&hist[(pk & 127u) * NCHK + (pk >> 24)], 1);
    }
    __syncthreads();
    // exclusive scan over the 1792 (padded) keys
    int kb = tid * SKPT;
    int sum = 0;
#pragma unroll
    for (int j = 0; j < SKPT; j++) sum += hist[kb + j];
    sbuf[tid] = sum;
    __syncthreads();
    for (int off = 1; off < 256; off <<= 1) {
        int tv = (tid >= off) ? sbuf[tid - off] : 0;
        __syncthreads();
        sbuf[tid] += tv;
        __syncthreads();
    }
    int run = sbuf[tid] - sum + substart;   // global cursor for own keys
#pragma unroll
    for (int j = 0; j < SKPT; j++) {
        int c = hist[kb + j];
        hist[kb + j] = run;
        run += c;
    }
    __syncthreads();
    // rows: start = cursor at key l*NCHK (read BEFORE placement mutates)
    if (tid < SUBN) {
        int l = tid;
        int rs = hist[l * NCHK];
        int re = (l == SUBN - 1) ? subend : hist[(l + 1) * NCHK];
        int n = (sub << SUBSH) + l;
        if (n < NNODES) {
            row_ptr[n] = rs;
            int c = re - rs;
            inv_in[n] = rsqrtf((float)(c < 1 ? 1 : c));
        }
    }
    __syncthreads();
    // placement into LDS staging (reads own range only; no global writes yet)
    if (sz <= SMAX) {
        for (int p = substart + tid; p < subend; p += 256) {
            float2 rec = data[p];
            unsigned pk = __float_as_uint(rec.y);
            int pos = atomicAdd(&hist[(pk & 127u) * NCHK + (pk >> 24)], 1);
            stout[pos - substart] = make_float2(rec.x, __int_as_float((int)(pk >> LBITS)));
        }
        __syncthreads();
        // coalesced copy-out (all reads of own range completed above)
        for (int i = tid; i < sz; i += 256)
            data[substart + i] = stout[i];
    } else {
        // overflow fallback (statistically unreachable: SMAX = mean + 16 sigma)
        for (int p = substart + tid; p < subend; p += 256) {
            float2 rec = data[p];
            unsigned pk = __float_as_uint(rec.y);
            int pos = atomicAdd(&hist[(pk & 127u) * NCHK + (pk >> 24)], 1);
            data[pos] = make_float2(rec.x, __int_as_float((int)(pk >> LBITS)));
        }
    }
}

// ---------------------------------------------------------------------------
// K5: hs[n,:] = (A[n,:] @ W_emb + b_emb) * inv_sqrt_out[n], padded rows
// ---------------------------------------------------------------------------
__global__ void k_embed(const float* __restrict__ A,
                        const float* __restrict__ Wemb,
                        const float* __restrict__ bemb,
                        const float* __restrict__ inv_out,
                        float* __restrict__ hs) {
    __shared__ float sW[FIN * WID];
    __shared__ float sb[WID];
    for (int i = threadIdx.x; i < FIN * WID; i += blockDim.x) sW[i] = Wemb[i];
    if (threadIdx.x < WID) sb[threadIdx.x] = bemb[threadIdx.x];
    __syncthreads();

    int n = blockIdx.x * blockDim.x + threadIdx.x;
    if (n >= NNODES) return;

    float acc[WID];
#pragma unroll
    for (int k = 0; k < WID; k++) acc[k] = sb[k];

    const float4* row4 = reinterpret_cast<const float4*>(A + (size_t)n * FIN);
#pragma unroll
    for (int f4 = 0; f4 < FIN / 4; f4++) {
        float4 v = row4[f4];
        int f = f4 * 4;
#pragma unroll
        for (int k = 0; k < WID; k++) acc[k] += v.x * sW[(f + 0) * WID + k];
#pragma unroll
        for (int k = 0; k < WID; k++) acc[k] += v.y * sW[(f + 1) * WID + k];
#pragma unroll
        for (int k = 0; k < WID; k++) acc[k] += v.z * sW[(f + 2) * WID + k];
#pragma unroll
        for (int k = 0; k < WID; k++) acc[k] += v.w * sW[(f + 3) * WID + k];
    }

    float sc = inv_out[n];
    float* out = hs + (size_t)n * HPAD;
    float4 o0 = make_float4(acc[0] * sc, acc[1] * sc, acc[2] * sc, acc[3] * sc);
    float4 o1 = make_float4(acc[4] * sc, acc[5] * sc, acc[6] * sc, acc[7] * sc);
    float2 o2 = make_float2(acc[8] * sc, acc[9] * sc);
    *reinterpret_cast<float4*>(out + 0) = o0;
    *reinterpret_cast<float4*>(out + 4) = o1;
    *reinterpret_cast<float2*>(out + 8) = o2;
}

// ---------------------------------------------------------------------------
// K7: pull-mode aggregate of gconv1 FUSED with node update + gconv2 proj.
// 8 lanes per node (round-8), phase-locked chunk walk, butterfly reduce.
// ---------------------------------------------------------------------------
__global__ void k_agg1(const float2* __restrict__ csr,
                       const int* __restrict__ row_ptr,
                       const float* __restrict__ hs,
                       const float* __restrict__ W1,
                       const float* __restrict__ b1,
                       const float* __restrict__ W2,
                       const float* __restrict__ inv_in,
                       const float* __restrict__ inv_out,
                       float* __restrict__ sproj) {
    __shared__ float sW1[WID * WID];
    __shared__ float sb1[WID];
    __shared__ float sW2[WID];
    for (int i = threadIdx.x; i < WID * WID; i += blockDim.x) sW1[i] = W1[i];
    if (threadIdx.x < WID) {
        sb1[threadIdx.x] = b1[threadIdx.x];
        sW2[threadIdx.x] = W2[threadIdx.x];
    }
    __syncthreads();

    int tid = threadIdx.x;
    int sub = tid & (LPN - 1);
    int n = blockIdx.x * NPB + (tid >> LPNSH);   // all n < NNODES (6250*32 exact)

    int start = row_ptr[n];
    int end = (n == NNODES - 1) ? NEDGES : row_ptr[n + 1];

    float acc[WID];
#pragma unroll
    for (int k = 0; k < WID; k++) acc[k] = 0.0f;

    int p = start + sub;
    for (int c = 0; c < NCHK; c++) {
        int slim = (c + 1) << CHBITS;
        while (p < end) {
            float2 c2 = csr[p];
            int s = __float_as_int(c2.y);
            if (s >= slim) break;
            float w = c2.x;
            const float* hrow = hs + (size_t)s * HPAD;
            float4 a = *reinterpret_cast<const float4*>(hrow + 0);
            float4 b = *reinterpret_cast<const float4*>(hrow + 4);
            float2 cc = *reinterpret_cast<const float2*>(hrow + 8);
            acc[0] += w * a.x; acc[1] += w * a.y; acc[2] += w * a.z; acc[3] += w * a.w;
            acc[4] += w * b.x; acc[5] += w * b.y; acc[6] += w * b.z; acc[7] += w * b.w;
            acc[8] += w * cc.x; acc[9] += w * cc.y;
            p += LPN;
        }
        __syncthreads();   // phase barrier: whole block advances chunk together
    }
    // drain (should be empty: chunk 12 covers all src < 13*16384)
    for (; p < end; p += LPN) {
        float2 c2 = csr[p];
        float w = c2.x;
        int s = __float_as_int(c2.y);
        const float* hrow = hs + (size_t)s * HPAD;
        float4 a = *reinterpret_cast<const float4*>(hrow + 0);
        float4 b = *reinterpret_cast<const float4*>(hrow + 4);
        float2 cc = *reinterpret_cast<const float2*>(hrow + 8);
        acc[0] += w * a.x; acc[1] += w * a.y; acc[2] += w * a.z; acc[3] += w * a.w;
        acc[4] += w * b.x; acc[5] += w * b.y; acc[6] += w * b.z; acc[7] += w * b.w;
        acc[8] += w * cc.x; acc[9] += w * cc.y;
    }

    // butterfly reduce across the 8-lane group; every lane ends with the sum
#pragma unroll
    for (int m = 1; m < LPN; m <<= 1) {
#pragma unroll
        for (int k = 0; k < WID; k++) acc[k] += __shfl_xor(acc[k], m, 64);
    }

    float ii = inv_in[n];
    float dot = 0.0f;
#pragma unroll
    for (int j = 0; j < WID; j++) {
        float y = 0.0f;
#pragma unroll
        for (int k = 0; k < WID; k++) y += acc[k] * sW1[k * WID + j];
        y = y * ii + sb1[j];
        y = y > 0.0f ? y : 0.0f;
        dot += y * sW2[j];
    }
    if (sub == 0) sproj[n] = dot * inv_out[n];
}

// ---------------------------------------------------------------------------
// K8: pull-mode scalar aggregate of gconv2 FUSED with graph pooling.
// 8 lanes per node; segmented reduce starts at offset LPN (sorted gids).
// __shfl clamps OOR lanes to SELF on AMD -> keep the lane+off<64 guard.
// ---------------------------------------------------------------------------
__global__ void k_agg2_pool(const float2* __restrict__ csr,
                            const int* __restrict__ row_ptr,
                            const float* __restrict__ sproj,
                            const float* __restrict__ inv_in,
                            const float* __restrict__ b2,
                            const int* __restrict__ graph_ids,
                            float* __restrict__ pooled) {
    int tid = threadIdx.x;
    int lane = tid & 63;
    int sub = tid & (LPN - 1);
    int n = blockIdx.x * NPB + (tid >> LPNSH);   // all n < NNODES

    int start = row_ptr[n];
    int end = (n == NNODES - 1) ? NEDGES : row_ptr[n + 1];
    float sum = 0.0f;
    for (int p = start + sub; p < end; p += LPN) {
        float2 c2 = csr[p];
        sum += c2.x * sproj[__float_as_int(c2.y)];
    }
#pragma unroll
    for (int m = 1; m < LPN; m <<= 1) sum += __shfl_xor(sum, m, 64);

    float v = sum * inv_in[n] + b2[0];
    int g = graph_ids[n];

    // segmented suffix-run reduce over the 8 node slots of the wave
#pragma unroll
    for (int off = LPN; off < 64; off <<= 1) {
        float vv = __shfl_down(v, off, 64);
        int gg = __shfl_down(g, off, 64);
        if (lane + off < 64 && gg == g) v += vv;
    }
    int gprev = __shfl_up(g, LPN, 64);
    bool head = (sub == 0) && (lane < LPN || gprev != g);
    if (head) atomicAdd(&pooled[g], v);
}

// ---------------------------------------------------------------------------
// K9: out[g] = pooled[g] / count(g); counts via binary search on sorted gids
// ---------------------------------------------------------------------------
__global__ void k_final(const float* __restrict__ pooled,
                        const int* __restrict__ gids,
                        float* __restrict__ out) {
    int g = blockIdx.x * blockDim.x + threadIdx.x;
    if (g >= NGRAPHS) return;
    int lo = 0, hi = NNODES;
    while (lo < hi) { int m = (lo + hi) >> 1; if (gids[m] < g) lo = m + 1; else hi = m; }
    int first = lo;
    hi = NNODES;
    while (lo < hi) { int m = (lo + hi) >> 1; if (gids[m] < g + 1) lo = m + 1; else hi = m; }
    int cnt = lo - first;
    out[g] = pooled[g] / (float)(cnt > 0 ? cnt : 1);
}

// ---------------------------------------------------------------------------
extern "C" void kernel_launch(void* const* d_in, const int* in_sizes, int n_in,
                              void* d_out, int out_size, void* d_ws, size_t ws_size,
                              hipStream_t stream) {
    const float* atom = (const float*)d_in[0];
    const float* r    = (const float*)d_in[1];
    const float* Wemb = (const float*)d_in[2];
    const float* bemb = (const float*)d_in[3];
    const float* W1   = (const float*)d_in[4];
    const float* b1   = (const float*)d_in[5];
    const float* W2   = (const float*)d_in[6];
    const float* b2   = (const float*)d_in[7];
    const int*   src  = (const int*)d_in[8];
    const int*   dst  = (const int*)d_in[9];
    const int*   gids = (const int*)d_in[10];
    float* out = (float*)d_out;

    // Workspace layout (16B-aligned chunks), ~122 MB total.
    char* w = (char*)d_ws;
    float* pooled  = (float*)w;  w += (size_t)NGRAPHS * 4;          // zeroed (2 KB)
    int*   subscan = (int*)w;    w += (size_t)NSUBP * 4;            // zeroed (6.4 KB)
    int*   subcur  = (int*)w;    w += (size_t)NSUBP * 4;
    int*   cnt     = (int*)w;    w += (size_t)CNT_N * 4;            // 1.6 MB
    int*   partial = (int*)w;    w += (size_t)((SBLKS + 3) & ~3) * 4;
    int*   row_ptr = (int*)w;    w += (size_t)((NNODES + 4) & ~3) * 4;
    float* inv_in  = (float*)w;  w += (size_t)NNODES * 4;
    float* inv_out = (float*)w;  w += (size_t)NNODES * 4;
    float* sproj   = (float*)w;  w += (size_t)NNODES * 4;
    float* hs      = (float*)w;  w += (size_t)NNODES * HPAD * 4;    // 12.8 MB
    float2* dstpart = (float2*)w; w += (size_t)NEDGES * 8;          // 51.2 MB
    float2* csrbuf  = (float2*)w; w += (size_t)NEDGES * 8;          // 51.2 MB
    // srcpart aliases csrbuf's first 12.8 MB: consumed by odeg BEFORE
    // k_refine writes dstfine into csrbuf; csr build then sorts IN PLACE.
    unsigned short* srcpart = (unsigned short*)csrbuf;

    hipMemsetAsync(pooled, 0, (size_t)NGRAPHS * 4, stream);
    hipMemsetAsync(subscan, 0, (size_t)NSUBP * 4, stream);

    const int B = 256;

    k_part_count<<<PBLK, B, 0, stream>>>(src, dst, cnt, subscan);
    k_scan_partial<<<SBLKS, B, 0, stream>>>(cnt, partial);
    k_scan_top<<<1, 1024, 0, stream>>>(partial);
    k_scan_apply<<<SBLKS, B, 0, stream>>>(cnt, partial);
    k_subscan<<<1, B, 0, stream>>>(subscan, subcur);
    k_part_scatter<<<PBLK, B, 0, stream>>>(r, src, dst, cnt, dstpart, srcpart);
    k_bucket_odeg<<<NB, B, 0, stream>>>(srcpart, cnt, inv_out);   // before refine (alias)
    k_refine<<<REF_GRID, B, 0, stream>>>(dstpart, cnt, subcur, csrbuf);
    k_bucket_csr<<<NSUB, B, 0, stream>>>(csrbuf, subscan, row_ptr, inv_in);
    k_embed<<<NBLK, B, 0, stream>>>(atom, Wemb, bemb, inv_out, hs);
    k_agg1<<<AGG_BLKS, B, 0, stream>>>(csrbuf, row_ptr, hs, W1, b1, W2, inv_in, inv_out, sproj);
    k_agg2_pool<<<AGG_BLKS, B, 0, stream>>>(csrbuf, row_ptr, sproj, inv_in, b2, gids, pooled);
    k_final<<<(NGRAPHS + B - 1) / B, B, 0, stream>>>(pooled, gids, out);
}